// Round 4
// baseline (1100.266 us; speedup 1.0000x reference)
//
#include <hip/hip_runtime.h>
#include <math.h>

#define BATCH 128
#define T 250
#define D_IN 700
#define H 256
#define D_OUT 20

typedef float v2f __attribute__((ext_vector_type(2)));
typedef __attribute__((ext_vector_type(8))) short bf16x8;
typedef __attribute__((ext_vector_type(4))) float f32x4;

static __device__ __forceinline__ unsigned short f2b(float f) {
    unsigned u = __float_as_uint(f);
    u += 0x7FFFu + ((u >> 16) & 1u);
    return (unsigned short)(u >> 16);
}

// Raw barrier: LDS ordering only (lgkmcnt). No vmcnt drain so global loads
// (u_nxt prefetch, gather pipeline) stay in flight across it.
static __device__ __forceinline__ void bar() {
    asm volatile("s_waitcnt lgkmcnt(0)" ::: "memory");
    __builtin_amdgcn_s_barrier();
    asm volatile("" ::: "memory");
}

// ---------------------------------------------------------------------------
// Workspace layout:
//   U     [32001][256] f32   (pad row: u-prefetch overrun at t=249)
//   C1    [257][512] f32     row k: q=2h -> W12T[k][h], q=2h+1 -> W11T[k][h]
//   C2    [257][512] f32     row k: q=2h -> W22T[k][h], q=2h+1 -> (h<20 ? Wo[h][k] : 0)
//   Wi1p  [256][704] bf16    cols 700..703 zero (MFMA K-pad)
//   row 256 of C1/C2 is all-zero (spike-list padding target)
//
// R4: TLP gather. 1024 threads = 4 row-groups x 256 column-pairs. Each wave
// of group 0 builds a wave-local compacted sublist; row-group g gathers
// sublist g (~n/4 rows) and LDS-reduces. In-flight rows per block = 16 waves
// x 16 = 256 vs R2's ~32, without fighting the register allocator.
// ---------------------------------------------------------------------------
#define N_C  (257 * 512)
#define N_WP (256 * 704)

__global__ void prep_k(const float* __restrict__ Wi1, const float* __restrict__ W11,
                       const float* __restrict__ W12, const float* __restrict__ W22,
                       const float* __restrict__ Wo,
                       unsigned short* __restrict__ Wi1p, float* __restrict__ C1,
                       float* __restrict__ C2) {
    int idx = blockIdx.x * 256 + threadIdx.x;
    if (idx < N_C) {
        int k = idx >> 9, q = idx & 511, h = q >> 1;
        float v = 0.f;
        if (k < H) v = (q & 1) ? W11[h * H + k] : W12[h * H + k];
        C1[idx] = v;
        return;
    }
    idx -= N_C;
    if (idx < N_C) {
        int k = idx >> 9, q = idx & 511, h = q >> 1;
        float v = 0.f;
        if (k < H) {
            if (q & 1) v = (h < D_OUT) ? Wo[h * H + k] : 0.f;
            else v = W22[h * H + k];
        }
        C2[idx] = v;
        return;
    }
    idx -= N_C;
    if (idx < N_WP) {
        int h = idx / 704, k = idx - h * 704;
        Wi1p[idx] = (k < D_IN) ? f2b(Wi1[h * D_IN + k]) : (unsigned short)0;
    }
}

// ---------------------------------------------------------------------------
// U = x @ Wi1^T + bi1 via MFMA 16x16x32 bf16 — UNCHANGED (proven).
// ---------------------------------------------------------------------------
__global__ __launch_bounds__(256) void gemm_u_k(const float* __restrict__ x,
                                                const unsigned short* __restrict__ Wi1p,
                                                const float* __restrict__ bi1,
                                                float* __restrict__ U) {
    const int lane = threadIdx.x & 63;
    const int wv = threadIdx.x >> 6;
    const int quad = lane >> 4;
    const int nl = lane & 15;
    const int mbase = blockIdx.x * 64 + wv * 16;
    const int m = mbase + nl;

    f32x4 acc[16];
#pragma unroll
    for (int i = 0; i < 16; ++i) acc[i] = (f32x4)(0.f);

    float bias[16];
#pragma unroll
    for (int nt = 0; nt < 16; ++nt) bias[nt] = bi1[nt * 16 + nl];

    const float* xrow = x + (size_t)m * D_IN;
    const unsigned short* brow = Wi1p + nl * 704 + quad * 8;

    for (int k0 = 0; k0 < 704; k0 += 32) {
        int ka = k0 + quad * 8;
        int ka2 = (ka + 4 <= 696) ? ka + 4 : 696;
        float4 q0 = *(const float4*)(xrow + ka);
        float4 q1 = *(const float4*)(xrow + ka2);
        bf16x8 af;
        af[0] = (short)f2b(q0.x); af[1] = (short)f2b(q0.y);
        af[2] = (short)f2b(q0.z); af[3] = (short)f2b(q0.w);
        af[4] = (short)f2b(q1.x); af[5] = (short)f2b(q1.y);
        af[6] = (short)f2b(q1.z); af[7] = (short)f2b(q1.w);

        const unsigned short* bp = brow + k0;
        bf16x8 bf[16];
#pragma unroll
        for (int nt = 0; nt < 16; ++nt)
            bf[nt] = *(const bf16x8*)(bp + nt * 16 * 704);
#pragma unroll
        for (int nt = 0; nt < 16; ++nt)
            acc[nt] = __builtin_amdgcn_mfma_f32_16x16x32_bf16(af, bf[nt], acc[nt], 0, 0, 0);
    }

#pragma unroll
    for (int nt = 0; nt < 16; ++nt) {
#pragma unroll
        for (int r = 0; r < 4; ++r) {
            U[(size_t)(mbase + quad * 4 + r) * H + nt * 16 + nl] = acc[nt][r] + bias[nt];
        }
    }
}

// ---------------------------------------------------------------------------
// Per-wave gather of one sublist (<= 64 rows, padded to mult of 16 with the
// all-zero row 256). Depth-16 chunks; compiler handles this depth naturally.
// ---------------------------------------------------------------------------
static __device__ __forceinline__ void ld16(const unsigned* __restrict__ lst, int o,
                                            const float* __restrict__ Cb, unsigned toff,
                                            v2f* buf) {
    uint4 a = *(const uint4*)(lst + o);
    uint4 b = *(const uint4*)(lst + o + 4);
    uint4 d = *(const uint4*)(lst + o + 8);
    uint4 e = *(const uint4*)(lst + o + 12);
    unsigned I[16] = {a.x, a.y, a.z, a.w, b.x, b.y, b.z, b.w,
                      d.x, d.y, d.z, d.w, e.x, e.y, e.z, e.w};
#pragma unroll
    for (int j = 0; j < 16; ++j)
        buf[j] = *(const v2f*)(Cb + (I[j] << 9) + toff);
}

static __device__ __forceinline__ void acc16(const v2f* buf, v2f& A0, v2f& A1) {
#pragma unroll
    for (int j = 0; j < 16; j += 2) { A0 += buf[j]; A1 += buf[j + 1]; }
}

static __device__ __forceinline__ v2f gatherS(const unsigned* __restrict__ lst, unsigned cc,
                                              const float* __restrict__ Cb, unsigned toff) {
    v2f A0 = (v2f)(0.f), A1 = (v2f)(0.f);
    if (cc == 0) return A0;                 // wave-uniform branch
    int nr = (int)((cc + 15u) & ~15u);      // 16..64
    v2f b[16];
    ld16(lst, 0, Cb, toff, b);
    for (int i = 16; i < nr; i += 16) {
        acc16(b, A0, A1);
        ld16(lst, i, Cb, toff, b);
    }
    acc16(b, A0, A1);
    return A0 + A1;
}

// ---------------------------------------------------------------------------
// Recurrent: one BLOCK (16 waves, 1024 threads) per batch element.
// Group 0 (waves 0-3): owns neuron state, builds wave-local spike sublists.
// All 4 row-groups gather their sublist; LDS reduce; wave 4 owns the output
// (memo/softmax) chain. 4 raw lgkm-only barriers per step.
// ---------------------------------------------------------------------------
__global__ __launch_bounds__(1024, 1) void recurrent_k(
    const float* __restrict__ U,
    const float* __restrict__ mem1_0, const float* __restrict__ mem2_0,
    const float* __restrict__ memo_0,
    const float* __restrict__ b11v, const float* __restrict__ b12v,
    const float* __restrict__ b22v, const float* __restrict__ bov,
    const float* __restrict__ tau_adp_h1, const float* __restrict__ tau_adp_h2,
    const float* __restrict__ tau_m_h1, const float* __restrict__ tau_m_h2,
    const float* __restrict__ tau_m_o,
    const float* __restrict__ C1, const float* __restrict__ C2,
    float* __restrict__ out)
{
    const int tid = threadIdx.x;
    const int lane = tid & 63;
    const int c = tid & 255;          // column pair (neuron id for group 0)
    const int g = tid >> 8;           // row group 0..3
    const int w4 = (tid >> 6) & 3;    // wave index within group
    const int wid = tid >> 6;         // global wave 0..15
    const int bi = blockIdx.x;
    const unsigned toff = 2u * (unsigned)c;
    const bool grp0 = (g == 0);

    __shared__ __align__(16) unsigned list1[4][80];
    __shared__ __align__(16) unsigned list2[4][80];
    __shared__ unsigned cnt1[4], cnt2[4];
    __shared__ __align__(16) v2f part[4][256];   // 8 KB, reused both layers

    // ---- group-0 neuron state ----
    float mem1 = 0.f, mem2 = 0.f, b1 = 0.01f, b2s = 0.01f;
    float spk1 = 0.f, spk2 = 0.f;
    float al1 = 0.f, ro1 = 0.f, al2 = 0.f, ro2 = 0.f;
    float oma1 = 0.f, omr1 = 0.f, oma2 = 0.f, omr2 = 0.f;
    float b11r = 0.f, bs2 = 0.f;
    if (grp0) {
        mem1 = mem1_0[bi * H + c];
        mem2 = mem2_0[bi * H + c];
        al1 = expf(-1.f / tau_m_h1[c]);
        ro1 = expf(-1.f / tau_adp_h1[c]);
        al2 = expf(-1.f / tau_m_h2[c]);
        ro2 = expf(-1.f / tau_adp_h2[c]);
        oma1 = 1.f - al1; omr1 = 1.f - ro1;
        oma2 = 1.f - al2; omr2 = 1.f - ro2;
        b11r = b11v[c];
        bs2 = b12v[c] + b22v[c];
    }

    // ---- wave-4 output state ----
    float memo = 0.f, alpha_o = 0.f, bo_r = 0.f, accv = 0.f, aOc = 0.f;
    if (wid == 4 && lane < D_OUT) {
        memo = memo_0[bi * D_OUT + lane];
        alpha_o = expf(-1.f / tau_m_o[lane]);
        bo_r = bov[lane];
    }

    float g11c = 0.f, g22c = 0.f;
    const float* Up = U + (size_t)bi * T * H + c;
    float u_cur = grp0 ? *Up : 0.f;
    const unsigned long long below = (1ull << lane) - 1ull;

    for (int t = 0; t < T; ++t) {
        // ---- wave 4: output chain for step t-1 (off group-0's path) ----
        if (wid == 4 && t >= 1) {
            float o = bo_r + aOc;
            memo = memo * alpha_o + (1.f - alpha_o) * o;
            if (t >= 12) {
                float e = (lane < D_OUT) ? __expf(memo) : 0.f;
                float s = e;
#pragma unroll
                for (int d = 16; d >= 1; d >>= 1) s += __shfl_xor(s, d, 32);
                if (lane < D_OUT) accv += __fdividef(e, s);
            }
        }

        // ---- group 0: layer-1 update + wave-local sublist build ----
        if (grp0) {
            float h1 = u_cur + b11r + g11c;
            b1 = ro1 * b1 + omr1 * spk1;
            float B1 = 0.01f + 1.8f * b1;
            mem1 = mem1 * al1 + oma1 * h1 - B1 * spk1;
            spk1 = (mem1 - B1 > 0.f) ? 1.f : 0.f;

            unsigned long long m1 = __ballot(spk1 != 0.f);
            unsigned cw = (unsigned)__popcll(m1);
            if (lane == 0) cnt1[w4] = cw;
            if (spk1 != 0.f) list1[w4][(unsigned)__popcll(m1 & below)] = (unsigned)c;
            if (lane < 16) list1[w4][cw + lane] = 256u;  // pads -> zero row
        }
        bar();   // A: list1 ready

        // u-prefetch in gather-1's shadow
        float u_nxt = 0.f;
        if (grp0) { u_nxt = Up[H]; }
        Up += H;

        v2f P1 = gatherS(list1[g], cnt1[g], C1, toff);   // {g12 part, g11 part}
        if (g) part[g][c] = P1;
        bar();   // B: layer-1 partials ready

        if (grp0) {
            v2f G1 = P1 + part[1][c] + part[2][c] + part[3][c];
            g11c = G1.y;

            // layer-2 update
            float h2 = bs2 + g22c + G1.x;
            b2s = ro2 * b2s + omr2 * spk2;
            float B2 = 0.01f + 1.8f * b2s;
            mem2 = mem2 * al2 + oma2 * h2 - B2 * spk2;
            spk2 = (mem2 - B2 > 0.f) ? 1.f : 0.f;

            unsigned long long m2 = __ballot(spk2 != 0.f);
            unsigned cw2 = (unsigned)__popcll(m2);
            if (lane == 0) cnt2[w4] = cw2;
            if (spk2 != 0.f) list2[w4][(unsigned)__popcll(m2 & below)] = (unsigned)c;
            if (lane < 16) list2[w4][cw2 + lane] = 256u;
        }
        bar();   // C: list2 ready

        v2f P2 = gatherS(list2[g], cnt2[g], C2, toff);   // {g22 part, aO part}
        part[g][c] = P2;                                  // all groups write (wave 4 needs g=0)
        bar();   // D: layer-2 partials ready

        if (grp0) {
            v2f G2 = P2 + part[1][c] + part[2][c] + part[3][c];
            g22c = G2.x;
        }
        if (wid == 4) {
            aOc = P2.y + part[0][lane].y + part[2][lane].y + part[3][lane].y;
        }
        u_cur = u_nxt;
    }

    // final flush (memo(T-1) + softmax) on wave 4
    if (wid == 4) {
        float o = bo_r + aOc;
        memo = memo * alpha_o + (1.f - alpha_o) * o;
        float e = (lane < D_OUT) ? __expf(memo) : 0.f;
        float s = e;
#pragma unroll
        for (int d = 16; d >= 1; d >>= 1) s += __shfl_xor(s, d, 32);
        if (lane < D_OUT) {
            accv += __fdividef(e, s);
            out[bi * D_OUT + lane] = accv;
        }
    }
}

// ---------------------------------------------------------------------------
extern "C" void kernel_launch(void* const* d_in, const int* in_sizes, int n_in,
                              void* d_out, int out_size, void* d_ws, size_t ws_size,
                              hipStream_t stream) {
    const float* x          = (const float*)d_in[0];
    const float* mem1_0     = (const float*)d_in[1];
    const float* mem2_0     = (const float*)d_in[2];
    const float* memo_0     = (const float*)d_in[3];
    const float* Wi1        = (const float*)d_in[4];
    const float* bi1        = (const float*)d_in[5];
    const float* W11        = (const float*)d_in[6];
    const float* b11        = (const float*)d_in[7];
    const float* W12        = (const float*)d_in[8];
    const float* b12        = (const float*)d_in[9];
    const float* W22        = (const float*)d_in[10];
    const float* b22        = (const float*)d_in[11];
    const float* Wo         = (const float*)d_in[12];
    const float* bo         = (const float*)d_in[13];
    const float* tau_adp_h1 = (const float*)d_in[14];
    const float* tau_adp_h2 = (const float*)d_in[15];
    const float* tau_m_h1   = (const float*)d_in[16];
    const float* tau_m_h2   = (const float*)d_in[17];
    const float* tau_m_o    = (const float*)d_in[18];

    float* U = (float*)d_ws;                            // [32001][256] f32
    float* C1 = U + ((size_t)BATCH * T + 1) * H;        // [257][512] f32
    float* C2 = C1 + N_C;                               // [257][512] f32
    unsigned short* Wi1p = (unsigned short*)(C2 + N_C); // [256][704] bf16

    int prep_total = 2 * N_C + N_WP;
    prep_k<<<(prep_total + 255) / 256, 256, 0, stream>>>(
        Wi1, W11, W12, W22, Wo, Wi1p, C1, C2);

    gemm_u_k<<<(BATCH * T) / 64, 256, 0, stream>>>(x, Wi1p, bi1, U);

    recurrent_k<<<BATCH, 1024, 0, stream>>>(U, mem1_0, mem2_0, memo_0,
                                            b11, b12, b22, bo,
                                            tau_adp_h1, tau_adp_h2,
                                            tau_m_h1, tau_m_h2, tau_m_o,
                                            C1, C2, (float*)d_out);
}

// Round 5
// 725.422 us; speedup vs baseline: 1.5167x; 1.5167x over previous
//
#include <hip/hip_runtime.h>
#include <math.h>

#define BATCH 128
#define T 250
#define D_IN 700
#define H 256
#define D_OUT 20

typedef float v2f __attribute__((ext_vector_type(2)));
typedef __attribute__((ext_vector_type(8))) short bf16x8;
typedef __attribute__((ext_vector_type(8))) unsigned short ushort8;
typedef __attribute__((ext_vector_type(4))) float f32x4;

static __device__ __forceinline__ unsigned short f2b(float f) {
    unsigned u = __float_as_uint(f);
    u += 0x7FFFu + ((u >> 16) & 1u);
    return (unsigned short)(u >> 16);
}

// Raw barrier: LDS ordering only (lgkmcnt). No vmcnt drain so global loads
// stay in flight across it.
static __device__ __forceinline__ void bar() {
    asm volatile("s_waitcnt lgkmcnt(0)" ::: "memory");
    __builtin_amdgcn_s_barrier();
    asm volatile("" ::: "memory");
}

// ---------------------------------------------------------------------------
// Workspace layout:
//   U     [32001][256] f32    (pad row: u-prefetch overrun at t=249)
//   C1    [257][512] bf16     row k, lane l: {W12T[k][4l..4l+3], W11T[k][4l..4l+3]}
//   C2    [257][512] bf16     row k, lane l: {W22T[k][4l..4l+3], Wo[l&31][k],0,0,0}
//   Wi1p  [256][704] bf16     cols 700..703 zero (MFMA K-pad)
//   row 256 of C1/C2 is all-zero (spike-list padding target)
//
// R5: bf16 weight tables (row = 1KB, ONE ushort8 load/row/lane) halve per-CU
// gather bytes; 4 waves stripe the spike list in 16-row chunks and LDS-reduce
// partials, spreading the bf16-unpack VALU across all 4 SIMDs. Wave 0 keeps
// the R7-proven 4-neurons/lane update + list build; wave 1 owns the output
// chain. 4 raw lgkm-only barriers/step.
// ---------------------------------------------------------------------------
#define N_C  (257 * 512)
#define N_WP (256 * 704)

__global__ void prep_k(const float* __restrict__ Wi1, const float* __restrict__ W11,
                       const float* __restrict__ W12, const float* __restrict__ W22,
                       const float* __restrict__ Wo,
                       unsigned short* __restrict__ Wi1p, unsigned short* __restrict__ C1,
                       unsigned short* __restrict__ C2) {
    int idx = blockIdx.x * 256 + threadIdx.x;
    if (idx < N_C) {
        int k = idx >> 9, q = idx & 511;
        int l = q >> 3, jj = q & 7;
        float v = 0.f;
        if (k < H) {
            int h = 4 * l + (jj & 3);
            v = (jj < 4) ? W12[h * H + k] : W11[h * H + k];
        }
        C1[idx] = f2b(v);
        return;
    }
    idx -= N_C;
    if (idx < N_C) {
        int k = idx >> 9, q = idx & 511;
        int l = q >> 3, jj = q & 7;
        float v = 0.f;
        if (k < H) {
            if (jj < 4) v = W22[(4 * l + jj) * H + k];
            else if (jj == 4 && (l & 31) < D_OUT) v = Wo[(l & 31) * H + k];
        }
        C2[idx] = f2b(v);
        return;
    }
    idx -= N_C;
    if (idx < N_WP) {
        int h = idx / 704, k = idx - h * 704;
        Wi1p[idx] = (k < D_IN) ? f2b(Wi1[h * D_IN + k]) : (unsigned short)0;
    }
}

// ---------------------------------------------------------------------------
// U = x @ Wi1^T + bi1 via MFMA 16x16x32 bf16 — UNCHANGED (proven).
// ---------------------------------------------------------------------------
__global__ __launch_bounds__(256) void gemm_u_k(const float* __restrict__ x,
                                                const unsigned short* __restrict__ Wi1p,
                                                const float* __restrict__ bi1,
                                                float* __restrict__ U) {
    const int lane = threadIdx.x & 63;
    const int wv = threadIdx.x >> 6;
    const int quad = lane >> 4;
    const int nl = lane & 15;
    const int mbase = blockIdx.x * 64 + wv * 16;
    const int m = mbase + nl;

    f32x4 acc[16];
#pragma unroll
    for (int i = 0; i < 16; ++i) acc[i] = (f32x4)(0.f);

    float bias[16];
#pragma unroll
    for (int nt = 0; nt < 16; ++nt) bias[nt] = bi1[nt * 16 + nl];

    const float* xrow = x + (size_t)m * D_IN;
    const unsigned short* brow = Wi1p + nl * 704 + quad * 8;

    for (int k0 = 0; k0 < 704; k0 += 32) {
        int ka = k0 + quad * 8;
        int ka2 = (ka + 4 <= 696) ? ka + 4 : 696;
        float4 q0 = *(const float4*)(xrow + ka);
        float4 q1 = *(const float4*)(xrow + ka2);
        bf16x8 af;
        af[0] = (short)f2b(q0.x); af[1] = (short)f2b(q0.y);
        af[2] = (short)f2b(q0.z); af[3] = (short)f2b(q0.w);
        af[4] = (short)f2b(q1.x); af[5] = (short)f2b(q1.y);
        af[6] = (short)f2b(q1.z); af[7] = (short)f2b(q1.w);

        const unsigned short* bp = brow + k0;
        bf16x8 bf[16];
#pragma unroll
        for (int nt = 0; nt < 16; ++nt)
            bf[nt] = *(const bf16x8*)(bp + nt * 16 * 704);
#pragma unroll
        for (int nt = 0; nt < 16; ++nt)
            acc[nt] = __builtin_amdgcn_mfma_f32_16x16x32_bf16(af, bf[nt], acc[nt], 0, 0, 0);
    }

#pragma unroll
    for (int nt = 0; nt < 16; ++nt) {
#pragma unroll
        for (int r = 0; r < 4; ++r) {
            U[(size_t)(mbase + quad * 4 + r) * H + nt * 16 + nl] = acc[nt][r] + bias[nt];
        }
    }
}

// ---------------------------------------------------------------------------
// Spike-list build by wave 0 (R7-proven): 4 ballots, compacted list + 64 pads
// pointing at the all-zero row 256.
// ---------------------------------------------------------------------------
__device__ __forceinline__ int build_list(unsigned int* list, int lane,
                                          float sx, float sy, float sz, float sw) {
    unsigned long long m0 = __ballot(sx > 0.f);
    unsigned long long m1 = __ballot(sy > 0.f);
    unsigned long long m2 = __ballot(sz > 0.f);
    unsigned long long m3 = __ballot(sw > 0.f);
    unsigned long long below = (1ull << lane) - 1ull;
    int c0 = __popcll(m0), c1 = __popcll(m1), c2 = __popcll(m2), c3 = __popcll(m3);
    int n = c0 + c1 + c2 + c3;
    if ((m0 >> lane) & 1) list[__popcll(m0 & below)] = lane * 4;
    if ((m1 >> lane) & 1) list[c0 + __popcll(m1 & below)] = lane * 4 + 1;
    if ((m2 >> lane) & 1) list[c0 + c1 + __popcll(m2 & below)] = lane * 4 + 2;
    if ((m3 >> lane) & 1) list[c0 + c1 + c2 + __popcll(m3 & below)] = lane * 4 + 3;
    list[n + lane] = 256;                   // 64 pad entries -> zero weight row
    __builtin_amdgcn_wave_barrier();
    return n;
}

// ---------------------------------------------------------------------------
// Striped per-wave gather: wave w takes 16-row chunks {c : (c/16)%4 == w}.
// Each row: ONE ushort8 (16B/lane) load covering the whole 1KB bf16 row.
// Two rotating 16-row buffers (64 VGPR live each) — R7's proven shape.
// ---------------------------------------------------------------------------
static __device__ __forceinline__ void ld16(const unsigned* __restrict__ lst, int c,
                                            const unsigned short* __restrict__ Cb,
                                            unsigned soff, ushort8* buf) {
    uint4 A = *(const uint4*)(lst + c);
    uint4 Bv = *(const uint4*)(lst + c + 4);
    uint4 Dv = *(const uint4*)(lst + c + 8);
    uint4 Ev = *(const uint4*)(lst + c + 12);
    unsigned I[16] = {A.x, A.y, A.z, A.w, Bv.x, Bv.y, Bv.z, Bv.w,
                      Dv.x, Dv.y, Dv.z, Dv.w, Ev.x, Ev.y, Ev.z, Ev.w};
#pragma unroll
    for (int j = 0; j < 16; ++j)
        buf[j] = *(const ushort8*)(Cb + ((unsigned)I[j] << 9) + soff);
}

static __device__ __forceinline__ void acc16(const ushort8* buf, v2f* a) {
#pragma unroll
    for (int j = 0; j < 16; ++j) {
        const unsigned* d = (const unsigned*)(buf + j);
#pragma unroll
        for (int q = 0; q < 4; ++q) {
            unsigned u = d[q];
            v2f t;
            t.x = __uint_as_float(u << 16);
            t.y = __uint_as_float(u & 0xffff0000u);
            a[q] += t;
        }
    }
}

static __device__ __forceinline__ void gatherQ(const unsigned* __restrict__ lst, int nr16,
                                               int w, const unsigned short* __restrict__ Cb,
                                               unsigned soff, v2f* a) {
    a[0] = (v2f)(0.f); a[1] = (v2f)(0.f); a[2] = (v2f)(0.f); a[3] = (v2f)(0.f);
    ushort8 wa[16], wb[16];
    const int c0 = w * 16, c1 = c0 + 64, c2v = c0 + 128, c3 = c0 + 192;
    const bool h0 = c0 < nr16, h1 = c1 < nr16, h2 = c2v < nr16, h3 = c3 < nr16;
    if (h0) ld16(lst, c0, Cb, soff, wa);
    if (h1) ld16(lst, c1, Cb, soff, wb);
    if (h0) acc16(wa, a);
    if (h2) ld16(lst, c2v, Cb, soff, wa);
    if (h1) acc16(wb, a);
    if (h3) ld16(lst, c3, Cb, soff, wb);
    if (h2) acc16(wa, a);
    if (h3) acc16(wb, a);
}

// ---------------------------------------------------------------------------
// Recurrent: one BLOCK (4 waves, 256 threads) per batch element.
// Wave 0: full neuron state (4 neurons/lane quads), list build, reduce.
// Waves 0-3: striped gathers + slot-major LDS partials (conflict-free b32).
// Wave 1: output (memo/softmax/acc) chain, off wave-0's critical path.
// ---------------------------------------------------------------------------
__global__ __launch_bounds__(256, 1) void recurrent_k(
    const float* __restrict__ U,
    const float* __restrict__ mem1_0, const float* __restrict__ mem2_0,
    const float* __restrict__ memo_0,
    const float* __restrict__ b11v, const float* __restrict__ b12v,
    const float* __restrict__ b22v, const float* __restrict__ bov,
    const float* __restrict__ tau_adp_h1, const float* __restrict__ tau_adp_h2,
    const float* __restrict__ tau_m_h1, const float* __restrict__ tau_m_h2,
    const float* __restrict__ tau_m_o,
    const unsigned short* __restrict__ C1, const unsigned short* __restrict__ C2,
    float* __restrict__ out)
{
    const int tid = threadIdx.x;
    const int lane = tid & 63;
    const int w = tid >> 6;
    const int bi = blockIdx.x;
    const unsigned laneOff = lane * 4;
    const unsigned soff = (unsigned)lane * 8;   // ushort offset into 512-elem row

    __shared__ __align__(16) unsigned list1[320], list2[320];
    __shared__ unsigned cnt1s, cnt2s;
    __shared__ float partS[8][4][64];           // slot-major: conflict-free b32

    // ---- wave-0 neuron state (quads, R7-proven) ----
    float4 mem1, mem2, b1, b2, spk1, spk2;
    float4 al1, ro1, al2, ro2, oma1, omr1, oma2, omr2, b11r, bsum2;
    if (w == 0) {
        mem1 = *(const float4*)(mem1_0 + bi * H + laneOff);
        mem2 = *(const float4*)(mem2_0 + bi * H + laneOff);
        b1 = make_float4(0.01f, 0.01f, 0.01f, 0.01f);
        b2 = make_float4(0.01f, 0.01f, 0.01f, 0.01f);
        spk1 = make_float4(0.f, 0.f, 0.f, 0.f);
        spk2 = make_float4(0.f, 0.f, 0.f, 0.f);
        float4 tm1 = *(const float4*)(tau_m_h1 + laneOff);
        float4 ta1 = *(const float4*)(tau_adp_h1 + laneOff);
        float4 tm2 = *(const float4*)(tau_m_h2 + laneOff);
        float4 ta2 = *(const float4*)(tau_adp_h2 + laneOff);
        al1.x = expf(-1.f / tm1.x); al1.y = expf(-1.f / tm1.y);
        al1.z = expf(-1.f / tm1.z); al1.w = expf(-1.f / tm1.w);
        ro1.x = expf(-1.f / ta1.x); ro1.y = expf(-1.f / ta1.y);
        ro1.z = expf(-1.f / ta1.z); ro1.w = expf(-1.f / ta1.w);
        al2.x = expf(-1.f / tm2.x); al2.y = expf(-1.f / tm2.y);
        al2.z = expf(-1.f / tm2.z); al2.w = expf(-1.f / tm2.w);
        ro2.x = expf(-1.f / ta2.x); ro2.y = expf(-1.f / ta2.y);
        ro2.z = expf(-1.f / ta2.z); ro2.w = expf(-1.f / ta2.w);
        oma1.x = 1.f - al1.x; oma1.y = 1.f - al1.y; oma1.z = 1.f - al1.z; oma1.w = 1.f - al1.w;
        omr1.x = 1.f - ro1.x; omr1.y = 1.f - ro1.y; omr1.z = 1.f - ro1.z; omr1.w = 1.f - ro1.w;
        oma2.x = 1.f - al2.x; oma2.y = 1.f - al2.y; oma2.z = 1.f - al2.z; oma2.w = 1.f - al2.w;
        omr2.x = 1.f - ro2.x; omr2.y = 1.f - ro2.y; omr2.z = 1.f - ro2.z; omr2.w = 1.f - ro2.w;
        b11r = *(const float4*)(b11v + laneOff);
        float4 b12r = *(const float4*)(b12v + laneOff);
        float4 b22r = *(const float4*)(b22v + laneOff);
        bsum2.x = b12r.x + b22r.x; bsum2.y = b12r.y + b22r.y;
        bsum2.z = b12r.z + b22r.z; bsum2.w = b12r.w + b22r.w;
    }

    // ---- wave-1 output state ----
    float memo = 0.f, alpha_o = 0.f, bo_r = 0.f, accv = 0.f;
    if (w == 1 && lane < D_OUT) {
        memo = memo_0[bi * D_OUT + lane];
        alpha_o = expf(-1.f / tau_m_o[lane]);
        bo_r = bov[lane];
    }

    float4 g11c = make_float4(0.f, 0.f, 0.f, 0.f);
    float4 g22c = make_float4(0.f, 0.f, 0.f, 0.f);

    const float* Up = U + (size_t)bi * T * H + laneOff;
    float4 u_cur;
    if (w == 0) u_cur = *(const float4*)Up;

    for (int t = 0; t < T; ++t) {
        // ---- wave 1: output chain for step t-1 (reads slot-4 partials) ----
        if (w == 1 && t >= 1) {
            float aOc = partS[4][0][lane] + partS[4][1][lane] +
                        partS[4][2][lane] + partS[4][3][lane];
            float o = bo_r + aOc;
            memo = memo * alpha_o + (1.f - alpha_o) * o;
            if (t >= 12) {
                float e = (lane < D_OUT) ? __expf(memo) : 0.f;
                float s = e;
#pragma unroll
                for (int d = 16; d >= 1; d >>= 1) s += __shfl_xor(s, d, 32);
                if (lane < D_OUT) accv += __fdividef(e, s);
            }
        }

        // ---- wave 0: layer-1 update + list 1 ----
        if (w == 0) {
            float4 h1;
            h1.x = u_cur.x + b11r.x + g11c.x; h1.y = u_cur.y + b11r.y + g11c.y;
            h1.z = u_cur.z + b11r.z + g11c.z; h1.w = u_cur.w + b11r.w + g11c.w;
            b1.x = ro1.x * b1.x + omr1.x * spk1.x; b1.y = ro1.y * b1.y + omr1.y * spk1.y;
            b1.z = ro1.z * b1.z + omr1.z * spk1.z; b1.w = ro1.w * b1.w + omr1.w * spk1.w;
            float B1x = 0.01f + 1.8f * b1.x, B1y = 0.01f + 1.8f * b1.y;
            float B1z = 0.01f + 1.8f * b1.z, B1w = 0.01f + 1.8f * b1.w;
            mem1.x = mem1.x * al1.x + oma1.x * h1.x - B1x * spk1.x;
            mem1.y = mem1.y * al1.y + oma1.y * h1.y - B1y * spk1.y;
            mem1.z = mem1.z * al1.z + oma1.z * h1.z - B1z * spk1.z;
            mem1.w = mem1.w * al1.w + oma1.w * h1.w - B1w * spk1.w;
            spk1.x = (mem1.x - B1x > 0.f) ? 1.f : 0.f;
            spk1.y = (mem1.y - B1y > 0.f) ? 1.f : 0.f;
            spk1.z = (mem1.z - B1z > 0.f) ? 1.f : 0.f;
            spk1.w = (mem1.w - B1w > 0.f) ? 1.f : 0.f;
            int n1 = build_list(list1, lane, spk1.x, spk1.y, spk1.z, spk1.w);
            if (lane == 0) cnt1s = (unsigned)n1;
        }
        bar();   // A: list1 + cnt ready

        // u-prefetch in gather-1's shadow
        float4 u_nxt;
        if (w == 0) u_nxt = *(const float4*)(Up + H);
        Up += H;

        int nr16a = (int)((cnt1s + 15u) & ~15u);
        v2f a1[4];
        gatherQ(list1, nr16a, w, C1, soff, a1);
#pragma unroll
        for (int q = 0; q < 4; ++q) {
            partS[2 * q][w][lane] = a1[q].x;
            partS[2 * q + 1][w][lane] = a1[q].y;
        }
        bar();   // B: layer-1 partials ready

        if (w == 0) {
            float g[8];
#pragma unroll
            for (int s = 0; s < 8; ++s)
                g[s] = a1[s >> 1][s & 1] + partS[s][1][lane] + partS[s][2][lane] +
                       partS[s][3][lane];
            g11c = make_float4(g[4], g[5], g[6], g[7]);

            float4 h2;
            h2.x = bsum2.x + g22c.x + g[0]; h2.y = bsum2.y + g22c.y + g[1];
            h2.z = bsum2.z + g22c.z + g[2]; h2.w = bsum2.w + g22c.w + g[3];
            b2.x = ro2.x * b2.x + omr2.x * spk2.x; b2.y = ro2.y * b2.y + omr2.y * spk2.y;
            b2.z = ro2.z * b2.z + omr2.z * spk2.z; b2.w = ro2.w * b2.w + omr2.w * spk2.w;
            float B2x = 0.01f + 1.8f * b2.x, B2y = 0.01f + 1.8f * b2.y;
            float B2z = 0.01f + 1.8f * b2.z, B2w = 0.01f + 1.8f * b2.w;
            mem2.x = mem2.x * al2.x + oma2.x * h2.x - B2x * spk2.x;
            mem2.y = mem2.y * al2.y + oma2.y * h2.y - B2y * spk2.y;
            mem2.z = mem2.z * al2.z + oma2.z * h2.z - B2z * spk2.z;
            mem2.w = mem2.w * al2.w + oma2.w * h2.w - B2w * spk2.w;
            spk2.x = (mem2.x - B2x > 0.f) ? 1.f : 0.f;
            spk2.y = (mem2.y - B2y > 0.f) ? 1.f : 0.f;
            spk2.z = (mem2.z - B2z > 0.f) ? 1.f : 0.f;
            spk2.w = (mem2.w - B2w > 0.f) ? 1.f : 0.f;
            int n2 = build_list(list2, lane, spk2.x, spk2.y, spk2.z, spk2.w);
            if (lane == 0) cnt2s = (unsigned)n2;
        }
        bar();   // C: list2 + cnt ready

        int nr16b = (int)((cnt2s + 15u) & ~15u);
        v2f a2[4];
        gatherQ(list2, nr16b, w, C2, soff, a2);
#pragma unroll
        for (int q = 0; q < 4; ++q) {
            partS[2 * q][w][lane] = a2[q].x;
            partS[2 * q + 1][w][lane] = a2[q].y;
        }
        bar();   // D: layer-2 partials ready

        if (w == 0) {
            g22c.x = a2[0].x + partS[0][1][lane] + partS[0][2][lane] + partS[0][3][lane];
            g22c.y = a2[0].y + partS[1][1][lane] + partS[1][2][lane] + partS[1][3][lane];
            g22c.z = a2[1].x + partS[2][1][lane] + partS[2][2][lane] + partS[2][3][lane];
            g22c.w = a2[1].y + partS[3][1][lane] + partS[3][2][lane] + partS[3][3][lane];
            u_cur = u_nxt;
        }
    }

    // final flush (memo(T-1) + softmax) on wave 1
    if (w == 1) {
        float aOc = partS[4][0][lane] + partS[4][1][lane] +
                    partS[4][2][lane] + partS[4][3][lane];
        float o = bo_r + aOc;
        memo = memo * alpha_o + (1.f - alpha_o) * o;
        float e = (lane < D_OUT) ? __expf(memo) : 0.f;
        float s = e;
#pragma unroll
        for (int d = 16; d >= 1; d >>= 1) s += __shfl_xor(s, d, 32);
        if (lane < D_OUT) {
            accv += __fdividef(e, s);
            out[bi * D_OUT + lane] = accv;
        }
    }
}

// ---------------------------------------------------------------------------
extern "C" void kernel_launch(void* const* d_in, const int* in_sizes, int n_in,
                              void* d_out, int out_size, void* d_ws, size_t ws_size,
                              hipStream_t stream) {
    const float* x          = (const float*)d_in[0];
    const float* mem1_0     = (const float*)d_in[1];
    const float* mem2_0     = (const float*)d_in[2];
    const float* memo_0     = (const float*)d_in[3];
    const float* Wi1        = (const float*)d_in[4];
    const float* bi1        = (const float*)d_in[5];
    const float* W11        = (const float*)d_in[6];
    const float* b11        = (const float*)d_in[7];
    const float* W12        = (const float*)d_in[8];
    const float* b12        = (const float*)d_in[9];
    const float* W22        = (const float*)d_in[10];
    const float* b22        = (const float*)d_in[11];
    const float* Wo         = (const float*)d_in[12];
    const float* bo         = (const float*)d_in[13];
    const float* tau_adp_h1 = (const float*)d_in[14];
    const float* tau_adp_h2 = (const float*)d_in[15];
    const float* tau_m_h1   = (const float*)d_in[16];
    const float* tau_m_h2   = (const float*)d_in[17];
    const float* tau_m_o    = (const float*)d_in[18];

    float* U = (float*)d_ws;                                       // [32001][256] f32
    unsigned short* C1 = (unsigned short*)(U + ((size_t)BATCH * T + 1) * H); // bf16
    unsigned short* C2 = C1 + N_C;                                 // bf16
    unsigned short* Wi1p = C2 + N_C;                               // bf16

    int prep_total = 2 * N_C + N_WP;
    prep_k<<<(prep_total + 255) / 256, 256, 0, stream>>>(
        Wi1, W11, W12, W22, Wo, Wi1p, C1, C2);

    gemm_u_k<<<(BATCH * T) / 64, 256, 0, stream>>>(x, Wi1p, bi1, U);

    recurrent_k<<<BATCH, 256, 0, stream>>>(U, mem1_0, mem2_0, memo_0,
                                           b11, b12, b22, bo,
                                           tau_adp_h1, tau_adp_h2,
                                           tau_m_h1, tau_m_h2, tau_m_o,
                                           C1, C2, (float*)d_out);
}